// Round 1
// baseline (98.130 us; speedup 1.0000x reference)
//
#include <hip/hip_runtime.h>
#include <math.h>

// Problem constants (match reference)
#define Lp 1024
#define Bp 64
#define TILES 16            // i-tiles per batch
#define ROWS_PER_TILE 64    // Lp / TILES
#define NJ 16               // j-slices per row-group
#define MI 4                // rows per thread
// threads/block = NJ * (ROWS_PER_TILE/MI) = 16 * 16 = 256

__global__ __launch_bounds__(256) void drmsd_main(
    const float* __restrict__ x, const float* __restrict__ y,
    float* __restrict__ partials)
{
    __shared__ float4 xs[Lp];
    __shared__ float4 ys[Lp];
    __shared__ float  ms[Lp];
    __shared__ float  red[4];

    const int b    = blockIdx.x;   // batch index
    const int tile = blockIdx.y;   // i-tile index
    const int t    = threadIdx.x;

    // ---- stage batch b's points into LDS: (x,y,z,|p|^2) + mask ----
#pragma unroll
    for (int k = 0; k < 4; ++k) {
        const int l = t + k * 256;
        const float* px = x + (size_t)l * (Bp * 3) + (size_t)b * 3;
        const float* py = y + (size_t)l * (Bp * 3) + (size_t)b * 3;
        const float x0 = px[0], x1 = px[1], x2 = px[2];
        const float y0 = py[0], y1 = py[1], y2 = py[2];
        const float sx = x0 * x0 + x1 * x1 + x2 * x2;
        const float sy = y0 * y0 + y1 * y1 + y2 * y2;
        xs[l] = make_float4(x0, x1, x2, sx);
        ys[l] = make_float4(y0, y1, y2, sy);
        ms[l] = ((y0 + y1 + y2) != 0.0f) ? 1.0f : 0.0f;
    }
    __syncthreads();

    const int jslice = t & (NJ - 1);      // 0..15
    const int rg     = t >> 4;            // 0..15
    const int i0     = tile * ROWS_PER_TILE + rg * MI;

    float4 xi[MI], yi[MI];
    float  acc[MI];
#pragma unroll
    for (int r = 0; r < MI; ++r) {
        xi[r]  = xs[i0 + r];
        yi[r]  = ys[i0 + r];
        acc[r] = 0.0f;
    }

    // ---- main loop over j (this thread's slice) ----
    for (int jj = 0; jj < Lp / NJ; ++jj) {
        const int j = jslice + jj * NJ;
        const float4 xj = xs[j];
        const float4 yj = ys[j];
        const float  mj = ms[j];
#pragma unroll
        for (int r = 0; r < MI; ++r) {
            const float dotx = xi[r].x * xj.x + xi[r].y * xj.y + xi[r].z * xj.z;
            const float d2x  = fmaf(-2.0f, dotx, xi[r].w + xj.w);
            const float dx   = __builtin_amdgcn_sqrtf(fmaxf(d2x, 0.0f));
            const float doty = yi[r].x * yj.x + yi[r].y * yj.y + yi[r].z * yj.z;
            const float d2y  = fmaf(-2.0f, doty, yi[r].w + yj.w);
            const float dy   = __builtin_amdgcn_sqrtf(fmaxf(d2y, 0.0f));
            const float w    = (j == i0 + r) ? 0.0f : mj;   // diagonal + col mask
            const float diff = (dy - dx) * w;
            acc[r] = fmaf(diff, diff, acc[r]);
        }
    }

    // ---- apply row mask, reduce block to one partial ----
    float tot = 0.0f;
#pragma unroll
    for (int r = 0; r < MI; ++r) tot += acc[r] * ms[i0 + r];

#pragma unroll
    for (int off = 32; off > 0; off >>= 1)
        tot += __shfl_down(tot, off, 64);
    const int wave = t >> 6;
    if ((t & 63) == 0) red[wave] = tot;
    __syncthreads();
    if (t == 0) {
        partials[(size_t)b * TILES + tile] = red[0] + red[1] + red[2] + red[3];
    }
}

__global__ __launch_bounds__(64) void drmsd_final(
    const float* __restrict__ partials, float* __restrict__ out)
{
    const int b = threadIdx.x;  // 64 threads = one wave, one per batch
    float s = 0.0f;
#pragma unroll
    for (int tidx = 0; tidx < TILES; ++tidx) s += partials[(size_t)b * TILES + tidx];
    float pb = sqrtf(s);
#pragma unroll
    for (int off = 32; off > 0; off >>= 1)
        pb += __shfl_down(pb, off, 64);
    if (b == 0) {
        const double denom = sqrt((double)Lp * (double)Lp / 2.0 - (double)Lp);
        out[0] = (float)((double)pb / denom / (double)Bp);
    }
}

extern "C" void kernel_launch(void* const* d_in, const int* in_sizes, int n_in,
                              void* d_out, int out_size, void* d_ws, size_t ws_size,
                              hipStream_t stream) {
    const float* x = (const float*)d_in[0];
    const float* y = (const float*)d_in[1];
    float* out      = (float*)d_out;
    float* partials = (float*)d_ws;   // Bp * TILES floats = 4 KB

    dim3 grid(Bp, TILES);
    drmsd_main<<<grid, 256, 0, stream>>>(x, y, partials);
    drmsd_final<<<1, 64, 0, stream>>>(partials, out);
}

// Round 2
// 76.073 us; speedup vs baseline: 1.2899x; 1.2899x over previous
//
#include <hip/hip_runtime.h>
#include <math.h>

// Problem constants (match reference)
#define Lp 1024
#define Bp 64
#define Tt 128          // tile rows
#define NTILE 8         // Lp / Tt
#define NPAIR 36        // NTILE*(NTILE+1)/2 triangular tile pairs

// Block: 256 threads, handles one (batch, tile-pair). Each thread computes a
// 4-row x 1-jslice strip over the 128x128 tile-pair: 2 halves x 8 jj x 4 rows
// = 64 pairs/thread. Diagonal pairs (i==j) contribute 0 naturally (d=0 both).
__global__ __launch_bounds__(256) void drmsd_main(
    const float* __restrict__ x, const float* __restrict__ y,
    float* __restrict__ partials)
{
    __shared__ float4 xs[2][Tt];   // [0]=i-tile, [1]=j-tile; (x0,x1,x2, unused)
    __shared__ float4 ys[2][Tt];   // (y0,y1,y2, mask)
    __shared__ float  red[4];

    const int b = blockIdx.x;      // batch
    const int p = blockIdx.y;      // triangular pair index 0..35

    // decode p -> (ti, tj), ti <= tj  (tiny scalar loop, once per block)
    int ti = 0, base = 0;
    while (p >= base + (NTILE - ti)) { base += (NTILE - ti); ++ti; }
    const int tj = ti + (p - base);

    const int t = threadIdx.x;

    // ---- stage the two tiles: threads 0-127 -> i-tile, 128-255 -> j-tile ----
    {
        const int r     = t & (Tt - 1);
        const int which = t >> 7;
        const int tile  = which ? tj : ti;
        const int row   = tile * Tt + r;
        const float* px = x + (size_t)row * (Bp * 3) + (size_t)b * 3;
        const float* py = y + (size_t)row * (Bp * 3) + (size_t)b * 3;
        const float x0 = px[0], x1 = px[1], x2 = px[2];
        const float y0 = py[0], y1 = py[1], y2 = py[2];
        const float m  = ((y0 + y1 + y2) != 0.0f) ? 1.0f : 0.0f;
        xs[which][r] = make_float4(x0, x1, x2, 0.0f);
        ys[which][r] = make_float4(y0, y1, y2, m);
    }
    __syncthreads();

    const int jslice = t & 15;     // 0..15
    const int rg     = t >> 4;     // 0..15
    float total = 0.0f;

#pragma unroll
    for (int ii = 0; ii < 2; ++ii) {
        const int i0 = ii * 64 + rg * 4;
        float4 xi[4], yi[4];
        float  acc[4];
#pragma unroll
        for (int r = 0; r < 4; ++r) {
            xi[r]  = xs[0][i0 + r];
            yi[r]  = ys[0][i0 + r];
            acc[r] = 0.0f;
        }
#pragma unroll
        for (int jj = 0; jj < 8; ++jj) {
            const int j = jj * 16 + jslice;
            const float4 xj = xs[1][j];
            const float4 yj = ys[1][j];
#pragma unroll
            for (int r = 0; r < 4; ++r) {
                const float ax = xi[r].x - xj.x;
                const float ay = xi[r].y - xj.y;
                const float az = xi[r].z - xj.z;
                const float d2x = ax * ax + ay * ay + az * az;  // exact >= 0
                const float dx  = __builtin_amdgcn_sqrtf(d2x);
                const float bx = yi[r].x - yj.x;
                const float by = yi[r].y - yj.y;
                const float bz = yi[r].z - yj.z;
                const float d2y = bx * bx + by * by + bz * bz;
                const float dy  = __builtin_amdgcn_sqrtf(d2y);
                const float dm  = (dy - dx) * yj.w;             // col mask
                acc[r] = fmaf(dm, dm, acc[r]);
            }
        }
#pragma unroll
        for (int r = 0; r < 4; ++r) total = fmaf(acc[r], yi[r].w, total); // row mask
    }

    // ---- block reduction ----
#pragma unroll
    for (int off = 32; off > 0; off >>= 1)
        total += __shfl_down(total, off, 64);
    const int wave = t >> 6;
    if ((t & 63) == 0) red[wave] = total;
    __syncthreads();
    if (t == 0) {
        float s = red[0] + red[1] + red[2] + red[3];
        if (ti != tj) s *= 2.0f;   // off-diagonal tile-pair counted for both orders
        partials[(size_t)b * NPAIR + p] = s;
    }
}

__global__ __launch_bounds__(64) void drmsd_final(
    const float* __restrict__ partials, float* __restrict__ out)
{
    const int b = threadIdx.x;  // one lane per batch
    float s = 0.0f;
#pragma unroll
    for (int pidx = 0; pidx < NPAIR; ++pidx)
        s += partials[(size_t)b * NPAIR + pidx];
    float pb = sqrtf(s);
#pragma unroll
    for (int off = 32; off > 0; off >>= 1)
        pb += __shfl_down(pb, off, 64);
    if (b == 0) {
        const double denom = sqrt((double)Lp * (double)Lp / 2.0 - (double)Lp);
        out[0] = (float)((double)pb / denom / (double)Bp);
    }
}

extern "C" void kernel_launch(void* const* d_in, const int* in_sizes, int n_in,
                              void* d_out, int out_size, void* d_ws, size_t ws_size,
                              hipStream_t stream) {
    const float* x = (const float*)d_in[0];
    const float* y = (const float*)d_in[1];
    float* out      = (float*)d_out;
    float* partials = (float*)d_ws;   // Bp * NPAIR floats = 9216 B

    dim3 grid(Bp, NPAIR);
    drmsd_main<<<grid, 256, 0, stream>>>(x, y, partials);
    drmsd_final<<<1, 64, 0, stream>>>(partials, out);
}

// Round 3
// 75.485 us; speedup vs baseline: 1.3000x; 1.0078x over previous
//
#include <hip/hip_runtime.h>
#include <math.h>

// Problem constants (match reference)
#define Lp 1024
#define Bp 64
#define Tt 128          // tile rows
#define NTILE 8         // Lp / Tt
#define NPAIR 36        // NTILE*(NTILE+1)/2 triangular tile pairs

// One block = one (batch, triangular tile-pair). 256 threads.
// Thread layout: jslice = t&15 (handles 2 adjacent j columns x 4 jj steps),
// rg = t>>4 (row group), 2 halves x 4 rows each -> 64 pairs/thread.
// Key math: (dy-dx)^2 = d2x + d2y - 2*sqrt(d2x*d2y)  -> ONE sqrt per pair.
// d2 computed as sum of squared diffs (exactly >= 0, so no fmax/NaN guard).
// Column mask mj folded into the accumulate fma (zero marginal cost).
__global__ __launch_bounds__(256) void drmsd_main(
    const float* __restrict__ x, const float* __restrict__ y,
    float* __restrict__ partials)
{
    // SoA layout: two consecutive j columns read as one packed float2 (b64)
    __shared__ __align__(16) float xsx[2][Tt], xsy[2][Tt], xsz[2][Tt];
    __shared__ __align__(16) float ysx[2][Tt], ysy[2][Tt], ysz[2][Tt];
    __shared__ __align__(16) float ms[2][Tt];
    __shared__ float red[4];

    const int b = blockIdx.x;      // batch
    const int p = blockIdx.y;      // triangular pair index 0..35

    // decode p -> (ti, tj), ti <= tj
    int ti = 0, base = 0;
    while (p >= base + (NTILE - ti)) { base += (NTILE - ti); ++ti; }
    const int tj = ti + (p - base);

    const int t = threadIdx.x;

    // ---- stage: threads 0-127 -> i-tile (slot 0), 128-255 -> j-tile (slot 1)
    {
        const int r     = t & (Tt - 1);
        const int which = t >> 7;
        const int tile  = which ? tj : ti;
        const int row   = tile * Tt + r;
        const float* px = x + (size_t)row * (Bp * 3) + (size_t)b * 3;
        const float* py = y + (size_t)row * (Bp * 3) + (size_t)b * 3;
        const float x0 = px[0], x1 = px[1], x2 = px[2];
        const float y0 = py[0], y1 = py[1], y2 = py[2];
        xsx[which][r] = x0; xsy[which][r] = x1; xsz[which][r] = x2;
        ysx[which][r] = y0; ysy[which][r] = y1; ysz[which][r] = y2;
        ms[which][r]  = ((y0 + y1 + y2) != 0.0f) ? 1.0f : 0.0f;
    }
    __syncthreads();

    const int jsl2 = (t & 15) << 1;   // first of 2 adjacent j columns
    const int rg   = t >> 4;          // 0..15

    float total = 0.0f;

#pragma unroll
    for (int half = 0; half < 2; ++half) {
        const int i0 = half * 64 + rg * 4;
        const float4 v_xx = *(const float4*)&xsx[0][i0];
        const float4 v_xy = *(const float4*)&xsy[0][i0];
        const float4 v_xz = *(const float4*)&xsz[0][i0];
        const float4 v_yx = *(const float4*)&ysx[0][i0];
        const float4 v_yy = *(const float4*)&ysy[0][i0];
        const float4 v_yz = *(const float4*)&ysz[0][i0];
        const float4 v_mi = *(const float4*)&ms[0][i0];
        const float xix[4] = { v_xx.x, v_xx.y, v_xx.z, v_xx.w };
        const float xiy[4] = { v_xy.x, v_xy.y, v_xy.z, v_xy.w };
        const float xiz[4] = { v_xz.x, v_xz.y, v_xz.z, v_xz.w };
        const float yix[4] = { v_yx.x, v_yx.y, v_yx.z, v_yx.w };
        const float yiy[4] = { v_yy.x, v_yy.y, v_yy.z, v_yy.w };
        const float yiz[4] = { v_yz.x, v_yz.y, v_yz.z, v_yz.w };
        const float mir[4] = { v_mi.x, v_mi.y, v_mi.z, v_mi.w };

        float accA[4] = {0.f, 0.f, 0.f, 0.f};   // j lane 0
        float accB[4] = {0.f, 0.f, 0.f, 0.f};   // j lane 1

#pragma unroll
        for (int jj = 0; jj < 4; ++jj) {
            const int j0 = jj * 32 + jsl2;
            const float2 xjx = *(const float2*)&xsx[1][j0];
            const float2 xjy = *(const float2*)&xsy[1][j0];
            const float2 xjz = *(const float2*)&xsz[1][j0];
            const float2 yjx = *(const float2*)&ysx[1][j0];
            const float2 yjy = *(const float2*)&ysy[1][j0];
            const float2 yjz = *(const float2*)&ysz[1][j0];
            const float2 mj  = *(const float2*)&ms[1][j0];
#pragma unroll
            for (int r = 0; r < 4; ++r) {
                // --- j lane A ---
                const float axA = xix[r] - xjx.x;
                const float ayA = xiy[r] - xjy.x;
                const float azA = xiz[r] - xjz.x;
                const float dxA = fmaf(axA, axA, fmaf(ayA, ayA, azA * azA));
                const float bxA = yix[r] - yjx.x;
                const float byA = yiy[r] - yjy.x;
                const float bzA = yiz[r] - yjz.x;
                const float dyA = fmaf(bxA, bxA, fmaf(byA, byA, bzA * bzA));
                const float sA  = __builtin_amdgcn_sqrtf(dxA * dyA);
                const float uA  = fmaf(-2.0f, sA, dxA + dyA);
                accA[r] = fmaf(mj.x, uA, accA[r]);
                // --- j lane B ---
                const float axB = xix[r] - xjx.y;
                const float ayB = xiy[r] - xjy.y;
                const float azB = xiz[r] - xjz.y;
                const float dxB = fmaf(axB, axB, fmaf(ayB, ayB, azB * azB));
                const float bxB = yix[r] - yjx.y;
                const float byB = yiy[r] - yjy.y;
                const float bzB = yiz[r] - yjz.y;
                const float dyB = fmaf(bxB, bxB, fmaf(byB, byB, bzB * bzB));
                const float sB  = __builtin_amdgcn_sqrtf(dxB * dyB);
                const float uB  = fmaf(-2.0f, sB, dxB + dyB);
                accB[r] = fmaf(mj.y, uB, accB[r]);
            }
        }
#pragma unroll
        for (int r = 0; r < 4; ++r)
            total = fmaf(accA[r] + accB[r], mir[r], total);   // row mask
    }

    // ---- block reduction ----
#pragma unroll
    for (int off = 32; off > 0; off >>= 1)
        total += __shfl_down(total, off, 64);
    const int wave = t >> 6;
    if ((t & 63) == 0) red[wave] = total;
    __syncthreads();
    if (t == 0) {
        float s = red[0] + red[1] + red[2] + red[3];
        if (ti != tj) s *= 2.0f;   // off-diagonal pair counted for both orders
        partials[(size_t)b * NPAIR + p] = s;
    }
}

__global__ __launch_bounds__(64) void drmsd_final(
    const float* __restrict__ partials, float* __restrict__ out)
{
    const int b = threadIdx.x;  // one lane per batch
    float s = 0.0f;
#pragma unroll
    for (int pidx = 0; pidx < NPAIR; ++pidx)
        s += partials[(size_t)b * NPAIR + pidx];
    float pb = sqrtf(s);
#pragma unroll
    for (int off = 32; off > 0; off >>= 1)
        pb += __shfl_down(pb, off, 64);
    if (b == 0) {
        const double denom = sqrt((double)Lp * (double)Lp / 2.0 - (double)Lp);
        out[0] = (float)((double)pb / denom / (double)Bp);
    }
}

extern "C" void kernel_launch(void* const* d_in, const int* in_sizes, int n_in,
                              void* d_out, int out_size, void* d_ws, size_t ws_size,
                              hipStream_t stream) {
    const float* x = (const float*)d_in[0];
    const float* y = (const float*)d_in[1];
    float* out      = (float*)d_out;
    float* partials = (float*)d_ws;   // Bp * NPAIR floats = 9216 B

    dim3 grid(Bp, NPAIR);
    drmsd_main<<<grid, 256, 0, stream>>>(x, y, partials);
    drmsd_final<<<1, 64, 0, stream>>>(partials, out);
}

// Round 4
// 69.863 us; speedup vs baseline: 1.4046x; 1.0805x over previous
//
#include <hip/hip_runtime.h>
#include <math.h>

// Problem constants (match reference)
#define Lp 1024
#define Bp 64
#define Tt 128          // tile rows
#define NTILE 8         // Lp / Tt
#define NPAIR 36        // NTILE*(NTILE+1)/2 triangular tile pairs

typedef float v2 __attribute__((ext_vector_type(2)));
static __device__ __forceinline__ v2 splat2(float s) { v2 r; r.x = s; r.y = s; return r; }

// One block = one (batch, triangular tile-pair). 256 threads.
// Two adjacent j-columns processed as one float2 vector so the backend can
// select v_pk_{fma,add,mul}_f32 (VOP3P 2xfp32). One sqrt per pair via
// (dy-dx)^2 = d2x + d2y - 2*sqrt(d2x*d2y); diff-form d2 is exactly >= 0.
__global__ __launch_bounds__(256) void drmsd_main(
    const float* __restrict__ x, const float* __restrict__ y,
    float* __restrict__ partials)
{
    __shared__ __align__(16) float xsx[2][Tt], xsy[2][Tt], xsz[2][Tt];
    __shared__ __align__(16) float ysx[2][Tt], ysy[2][Tt], ysz[2][Tt];
    __shared__ __align__(16) float ms[2][Tt];
    __shared__ float red[4];

    const int b = blockIdx.x;      // batch
    const int p = blockIdx.y;      // triangular pair index 0..35

    // decode p -> (ti, tj), ti <= tj
    int ti = 0, base = 0;
    while (p >= base + (NTILE - ti)) { base += (NTILE - ti); ++ti; }
    const int tj = ti + (p - base);

    const int t = threadIdx.x;

    // ---- stage: threads 0-127 -> i-tile (slot 0), 128-255 -> j-tile (slot 1)
    {
        const int r     = t & (Tt - 1);
        const int which = t >> 7;
        const int tile  = which ? tj : ti;
        const int row   = tile * Tt + r;
        const float* px = x + (size_t)row * (Bp * 3) + (size_t)b * 3;
        const float* py = y + (size_t)row * (Bp * 3) + (size_t)b * 3;
        const float x0 = px[0], x1 = px[1], x2 = px[2];
        const float y0 = py[0], y1 = py[1], y2 = py[2];
        xsx[which][r] = x0; xsy[which][r] = x1; xsz[which][r] = x2;
        ysx[which][r] = y0; ysy[which][r] = y1; ysz[which][r] = y2;
        ms[which][r]  = ((y0 + y1 + y2) != 0.0f) ? 1.0f : 0.0f;
    }
    __syncthreads();

    const int jsl2 = (t & 15) << 1;   // first of 2 adjacent j columns (even)
    const int rg   = t >> 4;          // 0..15

    float total = 0.0f;
    const v2 neg2 = splat2(-2.0f);

#pragma unroll
    for (int half = 0; half < 2; ++half) {
        const int i0 = half * 64 + rg * 4;
        const float4 v_xx = *(const float4*)&xsx[0][i0];
        const float4 v_xy = *(const float4*)&xsy[0][i0];
        const float4 v_xz = *(const float4*)&xsz[0][i0];
        const float4 v_yx = *(const float4*)&ysx[0][i0];
        const float4 v_yy = *(const float4*)&ysy[0][i0];
        const float4 v_yz = *(const float4*)&ysz[0][i0];
        const float4 v_mi = *(const float4*)&ms[0][i0];
        const float xix[4] = { v_xx.x, v_xx.y, v_xx.z, v_xx.w };
        const float xiy[4] = { v_xy.x, v_xy.y, v_xy.z, v_xy.w };
        const float xiz[4] = { v_xz.x, v_xz.y, v_xz.z, v_xz.w };
        const float yix[4] = { v_yx.x, v_yx.y, v_yx.z, v_yx.w };
        const float yiy[4] = { v_yy.x, v_yy.y, v_yy.z, v_yy.w };
        const float yiz[4] = { v_yz.x, v_yz.y, v_yz.z, v_yz.w };
        const float mir[4] = { v_mi.x, v_mi.y, v_mi.z, v_mi.w };

        v2 acc[4];
#pragma unroll
        for (int r = 0; r < 4; ++r) acc[r] = splat2(0.0f);

#pragma unroll
        for (int jj = 0; jj < 4; ++jj) {
            const int j0 = jj * 32 + jsl2;
            const v2 xjx = *(const v2*)&xsx[1][j0];
            const v2 xjy = *(const v2*)&xsy[1][j0];
            const v2 xjz = *(const v2*)&xsz[1][j0];
            const v2 yjx = *(const v2*)&ysx[1][j0];
            const v2 yjy = *(const v2*)&ysy[1][j0];
            const v2 yjz = *(const v2*)&ysz[1][j0];
            const v2 mj  = *(const v2*)&ms[1][j0];
#pragma unroll
            for (int r = 0; r < 4; ++r) {
                const v2 ax = splat2(xix[r]) - xjx;
                const v2 ay = splat2(xiy[r]) - xjy;
                const v2 az = splat2(xiz[r]) - xjz;
                const v2 d2x = ax * ax + ay * ay + az * az;   // contracts to pk_fma
                const v2 bx = splat2(yix[r]) - yjx;
                const v2 by = splat2(yiy[r]) - yjy;
                const v2 bz = splat2(yiz[r]) - yjz;
                const v2 d2y = bx * bx + by * by + bz * bz;
                const v2 pr = d2x * d2y;                      // >= 0 exactly
                v2 sq;
                sq.x = __builtin_amdgcn_sqrtf(pr.x);
                sq.y = __builtin_amdgcn_sqrtf(pr.y);
                const v2 u = (d2x + d2y) + neg2 * sq;         // contracts to pk_fma
                acc[r] = mj * u + acc[r];                     // col mask, pk_fma
            }
        }
#pragma unroll
        for (int r = 0; r < 4; ++r)
            total = fmaf(acc[r].x + acc[r].y, mir[r], total); // row mask
    }

    // ---- block reduction ----
#pragma unroll
    for (int off = 32; off > 0; off >>= 1)
        total += __shfl_down(total, off, 64);
    const int wave = t >> 6;
    if ((t & 63) == 0) red[wave] = total;
    __syncthreads();
    if (t == 0) {
        float s = red[0] + red[1] + red[2] + red[3];
        if (ti != tj) s *= 2.0f;   // off-diagonal pair counted for both orders
        partials[(size_t)p * Bp + b] = s;   // [p][b] layout -> coalesced final
    }
}

__global__ __launch_bounds__(256) void drmsd_final(
    const float* __restrict__ partials, float* __restrict__ out)
{
    __shared__ float sums[256];
    const int t    = threadIdx.x;
    const int lane = t & 63;
    const int q    = t >> 6;       // wave 0..3 handles 9 p's each
    float s = 0.0f;
#pragma unroll
    for (int k = 0; k < 9; ++k) {
        const int pidx = q * 9 + k;
        s += partials[(size_t)pidx * Bp + lane];   // coalesced across lanes
    }
    sums[t] = s;
    __syncthreads();
    if (t < 64) {
        float v = sums[t] + sums[t + 64] + sums[t + 128] + sums[t + 192];
        float pb = sqrtf(v);
#pragma unroll
        for (int off = 32; off > 0; off >>= 1)
            pb += __shfl_down(pb, off, 64);
        if (t == 0) {
            const double denom = sqrt((double)Lp * (double)Lp / 2.0 - (double)Lp);
            out[0] = (float)((double)pb / denom / (double)Bp);
        }
    }
}

extern "C" void kernel_launch(void* const* d_in, const int* in_sizes, int n_in,
                              void* d_out, int out_size, void* d_ws, size_t ws_size,
                              hipStream_t stream) {
    const float* x = (const float*)d_in[0];
    const float* y = (const float*)d_in[1];
    float* out      = (float*)d_out;
    float* partials = (float*)d_ws;   // NPAIR * Bp floats = 9216 B

    dim3 grid(Bp, NPAIR);
    drmsd_main<<<grid, 256, 0, stream>>>(x, y, partials);
    drmsd_final<<<1, 256, 0, stream>>>(partials, out);
}